// Round 23
// baseline (251.688 us; speedup 1.0000x reference)
//
#include <hip/hip_runtime.h>

typedef unsigned short u16;
typedef __attribute__((ext_vector_type(8))) short bf16x8;
typedef __attribute__((ext_vector_type(4))) float f32x4;

struct __align__(8) us4 { u16 x, y, z, w; };

#define B_  4
#define S_  1024
#define D_  1024
#define H_  16
#define DK_ 64

__device__ __forceinline__ u16 f2bf(float x) {
    union { float f; unsigned int u; } c; c.f = x;
    unsigned int r = (c.u + 0x7FFFu + ((c.u >> 16) & 1u)) >> 16;
    return (u16)r;
}

__device__ __forceinline__ u16 f2bf_trunc(float x) {
    union { float f; unsigned int u; } c; c.f = x;
    return (u16)(c.u >> 16);
}

__device__ __forceinline__ float bf2f(u16 x) {
    union { unsigned int u; float f; } c; c.u = ((unsigned int)x) << 16;
    return c.f;
}

__device__ __forceinline__ void gload_lds16(const void* g, void* l) {
    __builtin_amdgcn_global_load_lds(
        (const __attribute__((address_space(1))) unsigned int*)g,
        (__attribute__((address_space(3))) unsigned int*)l, 16, 0, 0);
}

__device__ __forceinline__ void nt_store4(f32x4 v, float* p) {
    __builtin_nontemporal_store(v, (f32x4*)p);
}

// ---------------- merged convert: x tensors (blocks 0..12287) + weights (12288..13311) ----------------
__global__ __launch_bounds__(256) void cvt_all(const float* __restrict__ q, const float* __restrict__ k,
                                               const float* __restrict__ v,
                                               const float* __restrict__ w0, const float* __restrict__ w1,
                                               const float* __restrict__ w2, const float* __restrict__ w3,
                                               u16* __restrict__ xq, u16* __restrict__ xk, u16* __restrict__ xv,
                                               u16* __restrict__ t0, u16* __restrict__ t1,
                                               u16* __restrict__ t2, u16* __restrict__ t3) {
    __shared__ float t[64][65];
    int bid = blockIdx.x;
    int tid = threadIdx.x;
    if (bid < 12288) {
        int which = bid >> 12;            // 0..2
        int xb = bid & 4095;
        const float* src = (which == 0) ? q : (which == 1) ? k : v;
        u16* dst        = (which == 0) ? xq : (which == 1) ? xk : xv;
        int idx = (xb * 256 + tid) * 4;
        f32x4 f = *(const f32x4*)(src + idx);
        us4 o; o.x = f2bf(f[0]); o.y = f2bf(f[1]); o.z = f2bf(f[2]); o.w = f2bf(f[3]);
        *(us4*)(dst + idx) = o;
    } else {
        int rem = bid - 12288;            // 0..1023
        int z = rem >> 8;                 // 0..3
        int r2 = rem & 255;
        int kb = r2 >> 4, nb = r2 & 15;
        const float* W = (z == 0) ? w0 : (z == 1) ? w1 : (z == 2) ? w2 : w3;
        u16* T        = (z == 0) ? t0 : (z == 1) ? t1 : (z == 2) ? t2 : t3;
        int k0 = kb * 64, n0 = nb * 64;
        int r4 = tid >> 6, c = tid & 63;
#pragma unroll
        for (int i = 0; i < 16; i++) {
            int r = i * 4 + r4;
            t[r][c] = W[(size_t)(k0 + r) * 1024 + n0 + c];
        }
        __syncthreads();
#pragma unroll
        for (int i = 0; i < 16; i++) {
            int r = i * 4 + r4;
            T[(size_t)(n0 + r) * 1024 + k0 + c] = f2bf(t[c][r]);
        }
    }
}

// ---------------- 128xBN bf16 MFMA GEMM, BK=64, T2-swizzled ----------------
template <int BN, int MODE>
__device__ __forceinline__ void gemm_core(const u16* __restrict__ X, const u16* __restrict__ WT,
                                          const float* __restrict__ bias, void* __restrict__ outp,
                                          float scale, int bm, int bn) {
    constexpr int NS = BN / 32;
    extern __shared__ u16 smem[];
    u16* Al = smem;
    u16* Bl = smem + 128 * 64;
    int tid = threadIdx.x, l = tid & 63, w = tid >> 6;
    int lr = l & 15, lq = l >> 4;
    int wm = (w >> 1) * 64, wn = (w & 1) * (BN / 2);
    f32x4 acc[4][NS] = {};
    for (int kk = 0; kk < 1024; kk += 64) {
        __syncthreads();
#pragma unroll
        for (int i = 0; i < 4; i++) {
            int flat = tid * 16 + i * 4096;
            int row = flat >> 7, kb = flat & 127;
            int kbs = kb ^ ((row & 7) << 4);
            gload_lds16((const char*)X + ((size_t)(bm * 128 + row) * 2048 + (size_t)kk * 2 + kbs),
                        (char*)Al + flat);
        }
#pragma unroll
        for (int i = 0; i < BN / 32; i++) {
            int flat = tid * 16 + i * 4096;
            int row = flat >> 7, kb = flat & 127;
            int kbs = kb ^ ((row & 7) << 4);
            gload_lds16((const char*)WT + ((size_t)(bn * BN + row) * 2048 + (size_t)kk * 2 + kbs),
                        (char*)Bl + flat);
        }
        asm volatile("s_waitcnt vmcnt(0)" ::: "memory");
        __syncthreads();
#pragma unroll
        for (int kkk = 0; kkk < 2; kkk++) {
            bf16x8 af[4], bfr[NS];
            int colb = kkk * 64 + lq * 16;
#pragma unroll
            for (int ms = 0; ms < 4; ms++) {
                int row = wm + ms * 16 + lr;
                af[ms] = *(const bf16x8*)((const char*)Al + row * 128 + (colb ^ ((row & 7) << 4)));
            }
#pragma unroll
            for (int ns = 0; ns < NS; ns++) {
                int row = wn + ns * 16 + lr;
                bfr[ns] = *(const bf16x8*)((const char*)Bl + row * 128 + (colb ^ ((row & 7) << 4)));
            }
#pragma unroll
            for (int ms = 0; ms < 4; ms++)
#pragma unroll
                for (int ns = 0; ns < NS; ns++) {
                    if (MODE == 1)
                        acc[ms][ns] = __builtin_amdgcn_mfma_f32_16x16x32_bf16(af[ms], bfr[ns], acc[ms][ns], 0, 0, 0);
                    else
                        acc[ms][ns] = __builtin_amdgcn_mfma_f32_16x16x32_bf16(bfr[ns], af[ms], acc[ms][ns], 0, 0, 0);
                }
        }
    }
    if (MODE == 1) {
#pragma unroll
        for (int ns = 0; ns < NS; ns++) {
            int n = bn * BN + wn + ns * 16 + lr;
            float bv_ = bias[n];
            int h = n >> 6, dk = n & 63;
#pragma unroll
            for (int ms = 0; ms < 4; ms++) {
                int mbase = bm * 128 + wm + ms * 16 + lq * 4;
                u16* o = (u16*)outp;
                int b = mbase >> 10, s0 = mbase & 1023;
                us4 pk;
                pk.x = f2bf(acc[ms][ns][0] + bv_);
                pk.y = f2bf(acc[ms][ns][1] + bv_);
                pk.z = f2bf(acc[ms][ns][2] + bv_);
                pk.w = f2bf(acc[ms][ns][3] + bv_);
                *(us4*)(o + ((size_t)(b * H_ + h) * 64 + dk) * 1024 + s0) = pk;
            }
        }
    } else {
#pragma unroll
        for (int ns = 0; ns < NS; ns++) {
            int n0 = bn * BN + wn + ns * 16 + lq * 4;
            f32x4 bv4 = *(const f32x4*)(bias + n0);
#pragma unroll
            for (int ms = 0; ms < 4; ms++) {
                int m = bm * 128 + wm + ms * 16 + lr;
                if (MODE == 0) {
                    u16* o = (u16*)outp;
                    int h = n0 >> 6, dk = n0 & 63;
                    int b = m >> 10, s = m & 1023;
                    us4 pk;
                    pk.x = f2bf((acc[ms][ns][0] + bv4[0]) * scale);
                    pk.y = f2bf((acc[ms][ns][1] + bv4[1]) * scale);
                    pk.z = f2bf((acc[ms][ns][2] + bv4[2]) * scale);
                    pk.w = f2bf((acc[ms][ns][3] + bv4[3]) * scale);
                    *(us4*)(o + ((size_t)(b * H_ + h) * 1024 + s) * 64 + dk) = pk;
                } else {
                    float* o = (float*)outp;
                    f32x4 o4 = acc[ms][ns] + bv4;
                    *(f32x4*)(o + (size_t)m * 1024 + n0) = o4;
                }
            }
        }
    }
}

__global__ __launch_bounds__(256, 3) void gemm_qkv(const u16* __restrict__ Xq, const u16* __restrict__ Xk,
                                                   const u16* __restrict__ Xv,
                                                   const u16* __restrict__ Wq, const u16* __restrict__ Wk,
                                                   const u16* __restrict__ Wv,
                                                   const float* __restrict__ bq, const float* __restrict__ bk,
                                                   const float* __restrict__ bv,
                                                   u16* __restrict__ Qh, u16* __restrict__ Kh,
                                                   u16* __restrict__ VT) {
    int z = blockIdx.z;
    const u16* X = (z == 0) ? Xq : (z == 1) ? Xk : Xv;
    const u16* W = (z == 0) ? Wq : (z == 1) ? Wk : Wv;
    const float* bia = (z == 0) ? bq : (z == 1) ? bk : bv;
    if (z == 2)
        gemm_core<128, 1>(X, W, bia, (void*)VT, 1.0f, blockIdx.x, blockIdx.y);
    else if (z == 0)
        gemm_core<128, 0>(X, W, bia, (void*)Qh, 0.125f, blockIdx.x, blockIdx.y);
    else
        gemm_core<128, 0>(X, W, bia, (void*)Kh, 1.0f, blockIdx.x, blockIdx.y);
}

__global__ __launch_bounds__(256, 3) void gemm_out(const u16* __restrict__ X, const u16* __restrict__ WT,
                                                   const float* __restrict__ bias, float* __restrict__ outp) {
    gemm_core<64, 2>(X, WT, bias, outp, 1.0f, blockIdx.x, blockIdx.y);
}

// ---------------- fused attention v15: 4 PV chains, NO launch_bounds ----------------
// R21/R22: under __launch_bounds__(256,4) the compiler PINNED VGPR=64 and spilled any
// extra accumulator (FETCH 12MB->270MB of scratch RMW, attn 130->183us). R7's attn
// without bounds allocated 204 VGPR -> bounds removal frees the allocator. LDS (33KB)
// still caps residency at 4 blocks/CU, so occupancy is unchanged; the 4 chains now
// live in registers. Verify: VGPR>64, FETCH ~12MB.
__global__ void attn_fused(const u16* __restrict__ Qh, const u16* __restrict__ Kh,
                           const u16* __restrict__ VT,
                           float* __restrict__ attn_out, float* __restrict__ x_out) {
    __shared__ u16 P_lds[16 * 1024];
    __shared__ float reds[4][16];
    int tid = threadIdx.x, l = tid & 63, w = tid >> 6;
    int lr = l & 15, lq = l >> 4;

    for (int t = blockIdx.x; t < 4096; t += 1024) {
        int xcd = t & 7;
        int rest = t >> 3;
        int bh = ((rest & 7) << 3) | xcd;
        int q0 = (rest >> 3) * 16;
        const u16* qp = Qh + (size_t)bh * 65536;
        const u16* kp = Kh + (size_t)bh * 65536;
        const u16* vp = VT + (size_t)bh * 65536;

        bf16x8 bq0 = *(const bf16x8*)(qp + (q0 + lr) * 64 + lq * 8);
        bf16x8 bq1 = *(const bf16x8*)(qp + (q0 + lr) * 64 + 32 + lq * 8);

        float s = 0.f;
#pragma unroll 4
        for (int n = 0; n < 16; n++) {
            int kb = w * 256 + n * 16;
            bf16x8 a0 = *(const bf16x8*)(kp + (size_t)(kb + lr) * 64 + lq * 8);
            bf16x8 a1 = *(const bf16x8*)(kp + (size_t)(kb + lr) * 64 + 32 + lq * 8);
            f32x4 a = {};
            a = __builtin_amdgcn_mfma_f32_16x16x32_bf16(a0, bq0, a, 0, 0, 0);
            a = __builtin_amdgcn_mfma_f32_16x16x32_bf16(a1, bq1, a, 0, 0, 0);
            f32x4 e;
            e[0] = __expf(a[0]); e[1] = __expf(a[1]);
            e[2] = __expf(a[2]); e[3] = __expf(a[3]);
            s += e[0] + e[1] + e[2] + e[3];
            int col = w * 256 + n * 16 + lq * 4;
            us4 pk;
            pk.x = f2bf_trunc(e[0]); pk.y = f2bf_trunc(e[1]);
            pk.z = f2bf_trunc(e[2]); pk.w = f2bf_trunc(e[3]);
            *(us4*)&P_lds[lr * 1024 + (col ^ ((lr & 7) << 3))] = pk;
        }
        s += __shfl_xor(s, 16);
        s += __shfl_xor(s, 32);
        if (l < 16) reds[w][lr] = s;
        __syncthreads();

        // attn output: full 4KB coalesced rows, nontemporal (streaming)
        size_t abase = (size_t)bh * 1048576 + (size_t)q0 * 1024;
#pragma unroll
        for (int i = 0; i < 16; i++) {
            float inv_i = 1.0f / (reds[0][i] + reds[1][i] + reds[2][i] + reds[3][i]);
            us4 pk4 = *(const us4*)&P_lds[i * 1024 + ((tid * 4) ^ ((i & 7) << 3))];
            f32x4 o;
            o[0] = bf2f(pk4.x) * inv_i;
            o[1] = bf2f(pk4.y) * inv_i;
            o[2] = bf2f(pk4.z) * inv_i;
            o[3] = bf2f(pk4.w) * inv_i;
            nt_store4(o, attn_out + abase + (size_t)i * 1024 + tid * 4);
        }

        // PV: wave w computes dk strip [w*16, w*16+16) over full K=1024.
        // 4 independent accumulator chains, registers unconstrained.
        f32x4 pv0 = {}, pv1 = {}, pv2 = {}, pv3 = {};
#pragma unroll
        for (int kk = 0; kk < 32; kk += 4) {
            bf16x8 ap0 = *(const bf16x8*)&P_lds[lr * 1024 + ((kk * 32 + lq * 8) ^ ((lr & 7) << 3))];
            bf16x8 bv0 = *(const bf16x8*)(vp + (size_t)(w * 16 + lr) * 1024 + kk * 32 + lq * 8);
            pv0 = __builtin_amdgcn_mfma_f32_16x16x32_bf16(ap0, bv0, pv0, 0, 0, 0);
            bf16x8 ap1 = *(const bf16x8*)&P_lds[lr * 1024 + (((kk + 1) * 32 + lq * 8) ^ ((lr & 7) << 3))];
            bf16x8 bv1 = *(const bf16x8*)(vp + (size_t)(w * 16 + lr) * 1024 + (kk + 1) * 32 + lq * 8);
            pv1 = __builtin_amdgcn_mfma_f32_16x16x32_bf16(ap1, bv1, pv1, 0, 0, 0);
            bf16x8 ap2 = *(const bf16x8*)&P_lds[lr * 1024 + (((kk + 2) * 32 + lq * 8) ^ ((lr & 7) << 3))];
            bf16x8 bv2 = *(const bf16x8*)(vp + (size_t)(w * 16 + lr) * 1024 + (kk + 2) * 32 + lq * 8);
            pv2 = __builtin_amdgcn_mfma_f32_16x16x32_bf16(ap2, bv2, pv2, 0, 0, 0);
            bf16x8 ap3 = *(const bf16x8*)&P_lds[lr * 1024 + (((kk + 3) * 32 + lq * 8) ^ ((lr & 7) << 3))];
            bf16x8 bv3 = *(const bf16x8*)(vp + (size_t)(w * 16 + lr) * 1024 + (kk + 3) * 32 + lq * 8);
            pv3 = __builtin_amdgcn_mfma_f32_16x16x32_bf16(ap3, bv3, pv3, 0, 0, 0);
        }
        pv0 += pv1;
        pv2 += pv3;
        pv0 += pv2;

        int b = bh >> 4, h = bh & 15;
#pragma unroll
        for (int r = 0; r < 4; r++) {
            int row = lq * 4 + r;
            float inv = 1.0f / (reds[0][row] + reds[1][row] + reds[2][row] + reds[3][row]);
            __builtin_nontemporal_store(pv0[r] * inv,
                x_out + ((size_t)(b * 1024 + q0 + row)) * 1024 + h * 64 + w * 16 + lr);
        }
        __syncthreads();   // protect P_lds/reds before next tile's QK writes
    }
}

// ---------------- residual + LayerNorm -> bf16 ----------------
__global__ __launch_bounds__(256) void ln_kernel(const float* __restrict__ x, const float* __restrict__ resid,
                                                 const float* __restrict__ gamma, const float* __restrict__ beta,
                                                 u16* __restrict__ out) {
    __shared__ float as_[4], as2_[4];
    int row = blockIdx.x, tid = threadIdx.x;
    int l = tid & 63, w = tid >> 6;
    size_t base = (size_t)row * 1024 + tid * 4;
    f32x4 v = *(const f32x4*)(x + base);
    f32x4 rz = *(const f32x4*)(resid + base);
    v += rz;
    float s = v[0] + v[1] + v[2] + v[3];
    float s2 = v[0] * v[0] + v[1] * v[1] + v[2] * v[2] + v[3] * v[3];
#pragma unroll
    for (int off = 1; off < 64; off <<= 1) {
        s += __shfl_xor(s, off);
        s2 += __shfl_xor(s2, off);
    }
    if (l == 0) { as_[w] = s; as2_[w] = s2; }
    __syncthreads();
    s = as_[0] + as_[1] + as_[2] + as_[3];
    s2 = as2_[0] + as2_[1] + as2_[2] + as2_[3];
    float mean = s * (1.f / 1024.f);
    float var = s2 * (1.f / 1024.f) - mean * mean;
    float rs = rsqrtf(var + 1e-6f);
    f32x4 g = *(const f32x4*)(gamma + tid * 4);
    f32x4 bt = *(const f32x4*)(beta + tid * 4);
    us4 o;
    o.x = f2bf((v[0] - mean) * rs * g[0] + bt[0]);
    o.y = f2bf((v[1] - mean) * rs * g[1] + bt[1]);
    o.z = f2bf((v[2] - mean) * rs * g[2] + bt[2]);
    o.w = f2bf((v[3] - mean) * rs * g[3] + bt[3]);
    *(us4*)(out + base) = o;
}

extern "C" void kernel_launch(void* const* d_in, const int* in_sizes, int n_in,
                              void* d_out, int out_size, void* d_ws, size_t ws_size,
                              hipStream_t stream) {
    const float* query = (const float*)d_in[0];
    const float* key   = (const float*)d_in[1];
    const float* value = (const float*)d_in[2];
    const float* Wq    = (const float*)d_in[3];
    const float* bq    = (const float*)d_in[4];
    const float* Wk    = (const float*)d_in[5];
    const float* bk    = (const float*)d_in[6];
    const float* Wv    = (const float*)d_in[7];
    const float* bv    = (const float*)d_in[8];
    const float* Wo    = (const float*)d_in[9];
    const float* bo    = (const float*)d_in[10];
    const float* gamma = (const float*)d_in[11];
    const float* beta  = (const float*)d_in[12];

    char* ws = (char*)d_ws;
    u16* XQ  = (u16*)(ws + 0);
    u16* XK  = (u16*)(ws + 8388608);
    u16* XV  = (u16*)(ws + 16777216);
    u16* WQT = (u16*)(ws + 25165824);
    u16* WKT = (u16*)(ws + 27262976);
    u16* WVT = (u16*)(ws + 29360128);
    u16* WOT = (u16*)(ws + 31457280);
    u16* Qh  = (u16*)(ws + 33554432);
    u16* Kh  = (u16*)(ws + 41943040);
    u16* VT  = (u16*)(ws + 50331648);
    float* PV = (float*)(ws + 0);
    u16* LN  = (u16*)(ws + 16777216);

    float* outp = (float*)d_out;
    float* attn = outp + 4194304;

    cvt_all<<<dim3(13312), 256, 0, stream>>>(query, key, value, Wq, Wk, Wv, Wo,
                                             XQ, XK, XV, WQT, WKT, WVT, WOT);
    gemm_qkv<<<dim3(32, 8, 3), 256, 32768, stream>>>(XQ, XK, XV, WQT, WKT, WVT, bq, bk, bv, Qh, Kh, VT);
    attn_fused<<<dim3(1024), 256, 0, stream>>>(Qh, Kh, VT, attn, PV);
    ln_kernel<<<4096, 256, 0, stream>>>(PV, query, gamma, beta, LN);
    gemm_out<<<dim3(32, 16), 256, 24576, stream>>>(LN, WOT, bo, outp);
}

// Round 24
// 203.003 us; speedup vs baseline: 1.2398x; 1.2398x over previous
//
#include <hip/hip_runtime.h>

typedef unsigned short u16;
typedef __attribute__((ext_vector_type(8))) short bf16x8;
typedef __attribute__((ext_vector_type(4))) float f32x4;

struct __align__(8) us4 { u16 x, y, z, w; };

#define B_  4
#define S_  1024
#define D_  1024
#define H_  16
#define DK_ 64

__device__ __forceinline__ u16 f2bf(float x) {
    union { float f; unsigned int u; } c; c.f = x;
    unsigned int r = (c.u + 0x7FFFu + ((c.u >> 16) & 1u)) >> 16;
    return (u16)r;
}

__device__ __forceinline__ u16 f2bf_trunc(float x) {
    union { float f; unsigned int u; } c; c.f = x;
    return (u16)(c.u >> 16);
}

__device__ __forceinline__ float bf2f(u16 x) {
    union { unsigned int u; float f; } c; c.u = ((unsigned int)x) << 16;
    return c.f;
}

__device__ __forceinline__ void gload_lds16(const void* g, void* l) {
    __builtin_amdgcn_global_load_lds(
        (const __attribute__((address_space(1))) unsigned int*)g,
        (__attribute__((address_space(3))) unsigned int*)l, 16, 0, 0);
}

__device__ __forceinline__ void nt_store4(f32x4 v, float* p) {
    __builtin_nontemporal_store(v, (f32x4*)p);
}

// ---------------- merged convert: x tensors (blocks 0..12287) + weights (12288..13311) ----------------
__global__ __launch_bounds__(256) void cvt_all(const float* __restrict__ q, const float* __restrict__ k,
                                               const float* __restrict__ v,
                                               const float* __restrict__ w0, const float* __restrict__ w1,
                                               const float* __restrict__ w2, const float* __restrict__ w3,
                                               u16* __restrict__ xq, u16* __restrict__ xk, u16* __restrict__ xv,
                                               u16* __restrict__ t0, u16* __restrict__ t1,
                                               u16* __restrict__ t2, u16* __restrict__ t3) {
    __shared__ float t[64][65];
    int bid = blockIdx.x;
    int tid = threadIdx.x;
    if (bid < 12288) {
        int which = bid >> 12;            // 0..2
        int xb = bid & 4095;
        const float* src = (which == 0) ? q : (which == 1) ? k : v;
        u16* dst        = (which == 0) ? xq : (which == 1) ? xk : xv;
        int idx = (xb * 256 + tid) * 4;
        f32x4 f = *(const f32x4*)(src + idx);
        us4 o; o.x = f2bf(f[0]); o.y = f2bf(f[1]); o.z = f2bf(f[2]); o.w = f2bf(f[3]);
        *(us4*)(dst + idx) = o;
    } else {
        int rem = bid - 12288;            // 0..1023
        int z = rem >> 8;                 // 0..3
        int r2 = rem & 255;
        int kb = r2 >> 4, nb = r2 & 15;
        const float* W = (z == 0) ? w0 : (z == 1) ? w1 : (z == 2) ? w2 : w3;
        u16* T        = (z == 0) ? t0 : (z == 1) ? t1 : (z == 2) ? t2 : t3;
        int k0 = kb * 64, n0 = nb * 64;
        int r4 = tid >> 6, c = tid & 63;
#pragma unroll
        for (int i = 0; i < 16; i++) {
            int r = i * 4 + r4;
            t[r][c] = W[(size_t)(k0 + r) * 1024 + n0 + c];
        }
        __syncthreads();
#pragma unroll
        for (int i = 0; i < 16; i++) {
            int r = i * 4 + r4;
            T[(size_t)(n0 + r) * 1024 + k0 + c] = f2bf(t[c][r]);
        }
    }
}

// ---------------- 128xBN bf16 MFMA GEMM, BK=64, T2-swizzled ----------------
template <int BN, int MODE>
__device__ __forceinline__ void gemm_core(const u16* __restrict__ X, const u16* __restrict__ WT,
                                          const float* __restrict__ bias, void* __restrict__ outp,
                                          float scale, int bm, int bn) {
    constexpr int NS = BN / 32;
    extern __shared__ u16 smem[];
    u16* Al = smem;
    u16* Bl = smem + 128 * 64;
    int tid = threadIdx.x, l = tid & 63, w = tid >> 6;
    int lr = l & 15, lq = l >> 4;
    int wm = (w >> 1) * 64, wn = (w & 1) * (BN / 2);
    f32x4 acc[4][NS] = {};
    for (int kk = 0; kk < 1024; kk += 64) {
        __syncthreads();
#pragma unroll
        for (int i = 0; i < 4; i++) {
            int flat = tid * 16 + i * 4096;
            int row = flat >> 7, kb = flat & 127;
            int kbs = kb ^ ((row & 7) << 4);
            gload_lds16((const char*)X + ((size_t)(bm * 128 + row) * 2048 + (size_t)kk * 2 + kbs),
                        (char*)Al + flat);
        }
#pragma unroll
        for (int i = 0; i < BN / 32; i++) {
            int flat = tid * 16 + i * 4096;
            int row = flat >> 7, kb = flat & 127;
            int kbs = kb ^ ((row & 7) << 4);
            gload_lds16((const char*)WT + ((size_t)(bn * BN + row) * 2048 + (size_t)kk * 2 + kbs),
                        (char*)Bl + flat);
        }
        asm volatile("s_waitcnt vmcnt(0)" ::: "memory");
        __syncthreads();
#pragma unroll
        for (int kkk = 0; kkk < 2; kkk++) {
            bf16x8 af[4], bfr[NS];
            int colb = kkk * 64 + lq * 16;
#pragma unroll
            for (int ms = 0; ms < 4; ms++) {
                int row = wm + ms * 16 + lr;
                af[ms] = *(const bf16x8*)((const char*)Al + row * 128 + (colb ^ ((row & 7) << 4)));
            }
#pragma unroll
            for (int ns = 0; ns < NS; ns++) {
                int row = wn + ns * 16 + lr;
                bfr[ns] = *(const bf16x8*)((const char*)Bl + row * 128 + (colb ^ ((row & 7) << 4)));
            }
#pragma unroll
            for (int ms = 0; ms < 4; ms++)
#pragma unroll
                for (int ns = 0; ns < NS; ns++) {
                    if (MODE == 1)
                        acc[ms][ns] = __builtin_amdgcn_mfma_f32_16x16x32_bf16(af[ms], bfr[ns], acc[ms][ns], 0, 0, 0);
                    else
                        acc[ms][ns] = __builtin_amdgcn_mfma_f32_16x16x32_bf16(bfr[ns], af[ms], acc[ms][ns], 0, 0, 0);
                }
        }
    }
    if (MODE == 1) {
#pragma unroll
        for (int ns = 0; ns < NS; ns++) {
            int n = bn * BN + wn + ns * 16 + lr;
            float bv_ = bias[n];
            int h = n >> 6, dk = n & 63;
#pragma unroll
            for (int ms = 0; ms < 4; ms++) {
                int mbase = bm * 128 + wm + ms * 16 + lq * 4;
                u16* o = (u16*)outp;
                int b = mbase >> 10, s0 = mbase & 1023;
                us4 pk;
                pk.x = f2bf(acc[ms][ns][0] + bv_);
                pk.y = f2bf(acc[ms][ns][1] + bv_);
                pk.z = f2bf(acc[ms][ns][2] + bv_);
                pk.w = f2bf(acc[ms][ns][3] + bv_);
                *(us4*)(o + ((size_t)(b * H_ + h) * 64 + dk) * 1024 + s0) = pk;
            }
        }
    } else {
#pragma unroll
        for (int ns = 0; ns < NS; ns++) {
            int n0 = bn * BN + wn + ns * 16 + lq * 4;
            f32x4 bv4 = *(const f32x4*)(bias + n0);
#pragma unroll
            for (int ms = 0; ms < 4; ms++) {
                int m = bm * 128 + wm + ms * 16 + lr;
                if (MODE == 0) {
                    u16* o = (u16*)outp;
                    int h = n0 >> 6, dk = n0 & 63;
                    int b = m >> 10, s = m & 1023;
                    us4 pk;
                    pk.x = f2bf((acc[ms][ns][0] + bv4[0]) * scale);
                    pk.y = f2bf((acc[ms][ns][1] + bv4[1]) * scale);
                    pk.z = f2bf((acc[ms][ns][2] + bv4[2]) * scale);
                    pk.w = f2bf((acc[ms][ns][3] + bv4[3]) * scale);
                    *(us4*)(o + ((size_t)(b * H_ + h) * 1024 + s) * 64 + dk) = pk;
                } else {
                    float* o = (float*)outp;
                    f32x4 o4 = acc[ms][ns] + bv4;
                    *(f32x4*)(o + (size_t)m * 1024 + n0) = o4;
                }
            }
        }
    }
}

__global__ __launch_bounds__(256, 3) void gemm_qkv(const u16* __restrict__ Xq, const u16* __restrict__ Xk,
                                                   const u16* __restrict__ Xv,
                                                   const u16* __restrict__ Wq, const u16* __restrict__ Wk,
                                                   const u16* __restrict__ Wv,
                                                   const float* __restrict__ bq, const float* __restrict__ bk,
                                                   const float* __restrict__ bv,
                                                   u16* __restrict__ Qh, u16* __restrict__ Kh,
                                                   u16* __restrict__ VT) {
    int z = blockIdx.z;
    const u16* X = (z == 0) ? Xq : (z == 1) ? Xk : Xv;
    const u16* W = (z == 0) ? Wq : (z == 1) ? Wk : Wv;
    const float* bia = (z == 0) ? bq : (z == 1) ? bk : bv;
    if (z == 2)
        gemm_core<128, 1>(X, W, bia, (void*)VT, 1.0f, blockIdx.x, blockIdx.y);
    else if (z == 0)
        gemm_core<128, 0>(X, W, bia, (void*)Qh, 0.125f, blockIdx.x, blockIdx.y);
    else
        gemm_core<128, 0>(X, W, bia, (void*)Kh, 1.0f, blockIdx.x, blockIdx.y);
}

__global__ __launch_bounds__(256, 3) void gemm_out(const u16* __restrict__ X, const u16* __restrict__ WT,
                                                   const float* __restrict__ bias, float* __restrict__ outp) {
    gemm_core<64, 2>(X, WT, bias, outp, 1.0f, blockIdx.x, blockIdx.y);
}

// ---------------- fused attention v16: NON-persistent, no bounds, 4 PV chains ----------------
// R21-23: every PERSISTENT variant pins VGPR=64 and spills extra accumulators
// (FETCH 12->268MB). The non-persistent structure (R7) allocated 204 VGPR freely.
// Final chain-theory test in the proven allocator regime: 4096 blocks (XCD-swizzled,
// R13 mapping), no launch_bounds, nt stores, trunc pack, QK unroll-4, PV = 4 named
// independent chains. Gates: VGPR in [80,220], FETCH ~12MB. If gates pass and time
// is flat, the chain theory is dead -> revert to R20 best next round.
__global__ void attn_fused(const u16* __restrict__ Qh, const u16* __restrict__ Kh,
                           const u16* __restrict__ VT,
                           float* __restrict__ attn_out, float* __restrict__ x_out) {
    __shared__ u16 P_lds[16 * 1024];
    __shared__ float reds[4][16];
    int tid = threadIdx.x, l = tid & 63, w = tid >> 6;
    int lr = l & 15, lq = l >> 4;
    int wg = blockIdx.x;
    int xcd = wg & 7;
    int rest = wg >> 3;
    int q0 = (rest & 63) * 16;
    int bh = ((rest >> 6) << 3) | xcd;
    const u16* qp = Qh + (size_t)bh * 65536;
    const u16* kp = Kh + (size_t)bh * 65536;
    const u16* vp = VT + (size_t)bh * 65536;

    bf16x8 bq0 = *(const bf16x8*)(qp + (q0 + lr) * 64 + lq * 8);
    bf16x8 bq1 = *(const bf16x8*)(qp + (q0 + lr) * 64 + 32 + lq * 8);

    float s = 0.f;
#pragma unroll 4
    for (int n = 0; n < 16; n++) {
        int kb = w * 256 + n * 16;
        bf16x8 a0 = *(const bf16x8*)(kp + (size_t)(kb + lr) * 64 + lq * 8);
        bf16x8 a1 = *(const bf16x8*)(kp + (size_t)(kb + lr) * 64 + 32 + lq * 8);
        f32x4 a = {};
        a = __builtin_amdgcn_mfma_f32_16x16x32_bf16(a0, bq0, a, 0, 0, 0);
        a = __builtin_amdgcn_mfma_f32_16x16x32_bf16(a1, bq1, a, 0, 0, 0);
        f32x4 e;
        e[0] = __expf(a[0]); e[1] = __expf(a[1]);
        e[2] = __expf(a[2]); e[3] = __expf(a[3]);
        s += e[0] + e[1] + e[2] + e[3];
        int col = w * 256 + n * 16 + lq * 4;
        us4 pk;
        pk.x = f2bf_trunc(e[0]); pk.y = f2bf_trunc(e[1]);
        pk.z = f2bf_trunc(e[2]); pk.w = f2bf_trunc(e[3]);
        *(us4*)&P_lds[lr * 1024 + (col ^ ((lr & 7) << 3))] = pk;
    }
    s += __shfl_xor(s, 16);
    s += __shfl_xor(s, 32);
    if (l < 16) reds[w][lr] = s;
    __syncthreads();

    // attn output: full 4KB coalesced rows, nontemporal (streaming)
    size_t abase = (size_t)bh * 1048576 + (size_t)q0 * 1024;
#pragma unroll
    for (int i = 0; i < 16; i++) {
        float inv_i = 1.0f / (reds[0][i] + reds[1][i] + reds[2][i] + reds[3][i]);
        us4 pk4 = *(const us4*)&P_lds[i * 1024 + ((tid * 4) ^ ((i & 7) << 3))];
        f32x4 o;
        o[0] = bf2f(pk4.x) * inv_i;
        o[1] = bf2f(pk4.y) * inv_i;
        o[2] = bf2f(pk4.z) * inv_i;
        o[3] = bf2f(pk4.w) * inv_i;
        nt_store4(o, attn_out + abase + (size_t)i * 1024 + tid * 4);
    }

    // PV: wave w computes dk strip [w*16, w*16+16) over full K=1024.
    // 4 independent named accumulator chains in the free-allocator regime.
    f32x4 pv0 = {}, pv1 = {}, pv2 = {}, pv3 = {};
#pragma unroll
    for (int kk = 0; kk < 32; kk += 4) {
        bf16x8 ap0 = *(const bf16x8*)&P_lds[lr * 1024 + ((kk * 32 + lq * 8) ^ ((lr & 7) << 3))];
        bf16x8 bv0 = *(const bf16x8*)(vp + (size_t)(w * 16 + lr) * 1024 + kk * 32 + lq * 8);
        pv0 = __builtin_amdgcn_mfma_f32_16x16x32_bf16(ap0, bv0, pv0, 0, 0, 0);
        bf16x8 ap1 = *(const bf16x8*)&P_lds[lr * 1024 + (((kk + 1) * 32 + lq * 8) ^ ((lr & 7) << 3))];
        bf16x8 bv1 = *(const bf16x8*)(vp + (size_t)(w * 16 + lr) * 1024 + (kk + 1) * 32 + lq * 8);
        pv1 = __builtin_amdgcn_mfma_f32_16x16x32_bf16(ap1, bv1, pv1, 0, 0, 0);
        bf16x8 ap2 = *(const bf16x8*)&P_lds[lr * 1024 + (((kk + 2) * 32 + lq * 8) ^ ((lr & 7) << 3))];
        bf16x8 bv2 = *(const bf16x8*)(vp + (size_t)(w * 16 + lr) * 1024 + (kk + 2) * 32 + lq * 8);
        pv2 = __builtin_amdgcn_mfma_f32_16x16x32_bf16(ap2, bv2, pv2, 0, 0, 0);
        bf16x8 ap3 = *(const bf16x8*)&P_lds[lr * 1024 + (((kk + 3) * 32 + lq * 8) ^ ((lr & 7) << 3))];
        bf16x8 bv3 = *(const bf16x8*)(vp + (size_t)(w * 16 + lr) * 1024 + (kk + 3) * 32 + lq * 8);
        pv3 = __builtin_amdgcn_mfma_f32_16x16x32_bf16(ap3, bv3, pv3, 0, 0, 0);
    }
    pv0 += pv1;
    pv2 += pv3;
    pv0 += pv2;

    int b = bh >> 4, h = bh & 15;
#pragma unroll
    for (int r = 0; r < 4; r++) {
        int row = lq * 4 + r;
        float inv = 1.0f / (reds[0][row] + reds[1][row] + reds[2][row] + reds[3][row]);
        __builtin_nontemporal_store(pv0[r] * inv,
            x_out + ((size_t)(b * 1024 + q0 + row)) * 1024 + h * 64 + w * 16 + lr);
    }
}

// ---------------- residual + LayerNorm -> bf16 ----------------
__global__ __launch_bounds__(256) void ln_kernel(const float* __restrict__ x, const float* __restrict__ resid,
                                                 const float* __restrict__ gamma, const float* __restrict__ beta,
                                                 u16* __restrict__ out) {
    __shared__ float as_[4], as2_[4];
    int row = blockIdx.x, tid = threadIdx.x;
    int l = tid & 63, w = tid >> 6;
    size_t base = (size_t)row * 1024 + tid * 4;
    f32x4 v = *(const f32x4*)(x + base);
    f32x4 rz = *(const f32x4*)(resid + base);
    v += rz;
    float s = v[0] + v[1] + v[2] + v[3];
    float s2 = v[0] * v[0] + v[1] * v[1] + v[2] * v[2] + v[3] * v[3];
#pragma unroll
    for (int off = 1; off < 64; off <<= 1) {
        s += __shfl_xor(s, off);
        s2 += __shfl_xor(s2, off);
    }
    if (l == 0) { as_[w] = s; as2_[w] = s2; }
    __syncthreads();
    s = as_[0] + as_[1] + as_[2] + as_[3];
    s2 = as2_[0] + as2_[1] + as2_[2] + as2_[3];
    float mean = s * (1.f / 1024.f);
    float var = s2 * (1.f / 1024.f) - mean * mean;
    float rs = rsqrtf(var + 1e-6f);
    f32x4 g = *(const f32x4*)(gamma + tid * 4);
    f32x4 bt = *(const f32x4*)(beta + tid * 4);
    us4 o;
    o.x = f2bf((v[0] - mean) * rs * g[0] + bt[0]);
    o.y = f2bf((v[1] - mean) * rs * g[1] + bt[1]);
    o.z = f2bf((v[2] - mean) * rs * g[2] + bt[2]);
    o.w = f2bf((v[3] - mean) * rs * g[3] + bt[3]);
    *(us4*)(out + base) = o;
}

extern "C" void kernel_launch(void* const* d_in, const int* in_sizes, int n_in,
                              void* d_out, int out_size, void* d_ws, size_t ws_size,
                              hipStream_t stream) {
    const float* query = (const float*)d_in[0];
    const float* key   = (const float*)d_in[1];
    const float* value = (const float*)d_in[2];
    const float* Wq    = (const float*)d_in[3];
    const float* bq    = (const float*)d_in[4];
    const float* Wk    = (const float*)d_in[5];
    const float* bk    = (const float*)d_in[6];
    const float* Wv    = (const float*)d_in[7];
    const float* bv    = (const float*)d_in[8];
    const float* Wo    = (const float*)d_in[9];
    const float* bo    = (const float*)d_in[10];
    const float* gamma = (const float*)d_in[11];
    const float* beta  = (const float*)d_in[12];

    char* ws = (char*)d_ws;
    u16* XQ  = (u16*)(ws + 0);
    u16* XK  = (u16*)(ws + 8388608);
    u16* XV  = (u16*)(ws + 16777216);
    u16* WQT = (u16*)(ws + 25165824);
    u16* WKT = (u16*)(ws + 27262976);
    u16* WVT = (u16*)(ws + 29360128);
    u16* WOT = (u16*)(ws + 31457280);
    u16* Qh  = (u16*)(ws + 33554432);
    u16* Kh  = (u16*)(ws + 41943040);
    u16* VT  = (u16*)(ws + 50331648);
    float* PV = (float*)(ws + 0);
    u16* LN  = (u16*)(ws + 16777216);

    float* outp = (float*)d_out;
    float* attn = outp + 4194304;

    cvt_all<<<dim3(13312), 256, 0, stream>>>(query, key, value, Wq, Wk, Wv, Wo,
                                             XQ, XK, XV, WQT, WKT, WVT, WOT);
    gemm_qkv<<<dim3(32, 8, 3), 256, 32768, stream>>>(XQ, XK, XV, WQT, WKT, WVT, bq, bk, bv, Qh, Kh, VT);
    attn_fused<<<dim3(4096), 256, 0, stream>>>(Qh, Kh, VT, attn, PV);
    ln_kernel<<<4096, 256, 0, stream>>>(PV, query, gamma, beta, LN);
    gemm_out<<<dim3(32, 16), 256, 24576, stream>>>(LN, WOT, bo, outp);
}